// Round 5
// baseline (274.952 us; speedup 1.0000x reference)
//
#include <hip/hip_runtime.h>

// Problem: N=30, K=100, ALPHA=0.5, B=1048576
#define NROWS    1048576
#define TILE     32                         // rows per tile
#define NBLOCKS  2048
#define NTHREADS 256
#define TILES_PER_BLOCK 16                  // 32768 tiles / 2048 blocks

// Per-tile global byte sizes (contiguous rows)
#define DP_TILE_B (TILE * 224)              // 7168 = 7 x 1KB
#define S_TILE_B  (TILE * 124)              // 3968 = 3 x 1KB + 896B tail
#define BX_TILE_B (TILE * 8)                // 256  = 1 x 256B

// LDS layout inside one buffer (all 16B-aligned)
#define LDS_DP 0
#define LDS_S1 7168
#define LDS_S2 11136
#define LDS_BX 15104
#define BUF_B  15360                        // 15 KB per buffer, x3 buffers
// total static LDS = 3*15360 + 2048 (sm) = 48128 -> 3 blocks/CU

// Async global->LDS DMA. LDS dest = wave-uniform base (+ lane*width implicit).
#define GLDS16(g, l) __builtin_amdgcn_global_load_lds(                         \
    (const __attribute__((address_space(1))) void*)(g),                        \
    (__attribute__((address_space(3))) void*)(l), 16, 0, 0)
#define GLDS4(g, l) __builtin_amdgcn_global_load_lds(                          \
    (const __attribute__((address_space(1))) void*)(g),                        \
    (__attribute__((address_space(3))) void*)(l), 4, 0, 0)

// Staging split: wv0 -> 4 ops, wv1 -> 4 ops, wv2 -> 7 ops, wv3 -> 7 ops.
// S tail (3968B = 3x1KB + 896B): 3 GLDS16 + 4 GLDS4 at 3072/3328/3584/3712;
// the last overlaps the previous by 128B (same bytes, benign).
__device__ __forceinline__ void stage_tile(unsigned char* buf,
    const char* dpg, const char* s1g, const char* s2g, const char* bxg,
    int wv, int lane)
{
    if (wv == 0) {
        #pragma unroll
        for (int c = 0; c < 4; ++c)
            GLDS16(dpg + c * 1024 + lane * 16, buf + LDS_DP + c * 1024);
    } else if (wv == 1) {
        #pragma unroll
        for (int c = 4; c < 7; ++c)
            GLDS16(dpg + c * 1024 + lane * 16, buf + LDS_DP + c * 1024);
        GLDS4(bxg + lane * 4, buf + LDS_BX);
    } else if (wv == 2) {
        #pragma unroll
        for (int c = 0; c < 3; ++c)
            GLDS16(s1g + c * 1024 + lane * 16, buf + LDS_S1 + c * 1024);
        GLDS4(s1g + 3072 + lane * 4, buf + LDS_S1 + 3072);
        GLDS4(s1g + 3328 + lane * 4, buf + LDS_S1 + 3328);
        GLDS4(s1g + 3584 + lane * 4, buf + LDS_S1 + 3584);
        GLDS4(s1g + 3712 + lane * 4, buf + LDS_S1 + 3712);
    } else {
        #pragma unroll
        for (int c = 0; c < 3; ++c)
            GLDS16(s2g + c * 1024 + lane * 16, buf + LDS_S2 + c * 1024);
        GLDS4(s2g + 3072 + lane * 4, buf + LDS_S2 + 3072);
        GLDS4(s2g + 3328 + lane * 4, buf + LDS_S2 + 3328);
        GLDS4(s2g + 3584 + lane * 4, buf + LDS_S2 + 3584);
        GLDS4(s2g + 3712 + lane * 4, buf + LDS_S2 + 3712);
    }
}

// 128 threads compute: 4 lanes per row, 7 pairs each, shuffle-combine.
__device__ __forceinline__ void compute_tile(const unsigned char* buf,
    int row, int seg, float w, double& acc)
{
    const float*  s1row = (const float*)(buf + LDS_S1 + row * 124);
    const float*  s2row = (const float*)(buf + LDS_S2 + row * 124);
    const float2* dprow = (const float2*)(buf + LDS_DP + row * 224);
    const float2  b2    = *(const float2*)(buf + LDS_BX + row * 8);

    const int sb = 7 * seg;
    float s1v[9], s2v[9];
    #pragma unroll
    for (int i = 0; i < 9; ++i) { s1v[i] = s1row[sb + i]; s2v[i] = s2row[sb + i]; }

    float sum = 0.0f;
    #pragma unroll
    for (int u = 0; u < 7; ++u) {
        const float2 d = dprow[sb + u];     // (d1[p], d2[p]), p = sb+u
        sum += d.x * (s1v[u + 2] - s1v[u + 1]) + d.y * (s2v[u + 2] - s2v[u + 1]);
    }
    const float t0 = b2.x * (s1v[1] - s1v[0]) + b2.y * (s2v[1] - s2v[0]);
    sum += (seg == 0) ? t0 : 0.0f;

    sum += __shfl_xor(sum, 1);
    sum += __shfl_xor(sum, 2);

    const float liab = fmaxf(s1row[30] - 100.0f, 0.0f);
    const float loss = w + fmaxf(liab - sum - w, 0.0f) * 2.0f;   // /(1-ALPHA)
    if (seg == 0) acc += (double)loss;
}

__global__ __launch_bounds__(NTHREADS) void loss_pipe_kernel(
    const float* __restrict__ dp, const float* __restrict__ bx,
    const float* __restrict__ S1, const float* __restrict__ S2,
    const float* __restrict__ wp, double* __restrict__ partial,
    unsigned int* __restrict__ counter, float* __restrict__ out)
{
    __shared__ __align__(16) unsigned char lds[3 * BUF_B];
    __shared__ double sm[NTHREADS];
    __shared__ int last_flag;

    const int tid  = threadIdx.x;
    const int lane = tid & 63;
    const int wv   = tid >> 6;
    const int row  = (tid & 127) >> 2;      // 0..31 (tid<128 computes)
    const int seg  = tid & 3;               // 0..3
    const float w  = *wp;

    const long tile0 = (long)blockIdx.x * TILES_PER_BLOCK;
    double acc = 0.0;

    // prologue: stage tiles 0,1 into buf0,buf1
    #pragma unroll
    for (int p = 0; p < 2; ++p)
        stage_tile(lds + p * BUF_B,
                   (const char*)dp + (tile0 + p) * DP_TILE_B,
                   (const char*)S1 + (tile0 + p) * S_TILE_B,
                   (const char*)S2 + (tile0 + p) * S_TILE_B,
                   (const char*)bx + (tile0 + p) * BX_TILE_B, wv, lane);

    // main loop: ONE barrier per tile.
    //   wait(own tile-t ops) -> barrier -> stage(t+2) -> compute(t)
    // stage(t+2) writes buf[(t+2)%3] == buf[(t-1)%3]; every wave finished
    // reading that buffer in compute(t-1), which precedes this barrier.
    int cb = 0;                              // t % 3
    for (int t = 0; t < TILES_PER_BLOCK; ++t) {
        if (t < TILES_PER_BLOCK - 1) {
            if (wv < 2) asm volatile("s_waitcnt vmcnt(4)" ::: "memory");
            else        asm volatile("s_waitcnt vmcnt(7)" ::: "memory");
        } else {
            asm volatile("s_waitcnt vmcnt(0)" ::: "memory");
        }
        __builtin_amdgcn_s_barrier();
        if (t + 2 < TILES_PER_BLOCK) {
            const long nt = tile0 + t + 2;
            const int nb = (cb + 2 >= 3) ? cb - 1 : cb + 2;
            stage_tile(lds + nb * BUF_B,
                       (const char*)dp + nt * DP_TILE_B,
                       (const char*)S1 + nt * S_TILE_B,
                       (const char*)S2 + nt * S_TILE_B,
                       (const char*)bx + nt * BX_TILE_B, wv, lane);
        }
        if (tid < 128) compute_tile(lds + cb * BUF_B, row, seg, w, acc);
        cb = (cb == 2) ? 0 : cb + 1;
    }

    // deterministic block reduction (double)
    sm[tid] = acc;
    __syncthreads();
    #pragma unroll
    for (int s = NTHREADS / 2; s > 0; s >>= 1) {
        if (tid < s) sm[tid] += sm[tid + s];
        __syncthreads();
    }

    // last-block-elect final reduction (fused; saves a launch)
    if (tid == 0) {
        __hip_atomic_store(&partial[blockIdx.x], sm[0],
                           __ATOMIC_RELEASE, __HIP_MEMORY_SCOPE_AGENT);
        const unsigned int old = __hip_atomic_fetch_add(counter, 1u,
                           __ATOMIC_ACQ_REL, __HIP_MEMORY_SCOPE_AGENT);
        last_flag = (old == NBLOCKS - 1) ? 1 : 0;
    }
    __syncthreads();
    if (last_flag) {
        double a = 0.0;
        #pragma unroll
        for (int k = 0; k < NBLOCKS / NTHREADS; ++k)    // fixed order: 8 each
            a += __hip_atomic_load(&partial[tid * (NBLOCKS / NTHREADS) + k],
                                   __ATOMIC_RELAXED, __HIP_MEMORY_SCOPE_AGENT);
        __syncthreads();                                 // sm safe to reuse
        sm[tid] = a;
        __syncthreads();
        #pragma unroll
        for (int s = NTHREADS / 2; s > 0; s >>= 1) {
            if (tid < s) sm[tid] += sm[tid + s];
            __syncthreads();
        }
        if (tid == 0) out[0] = (float)(sm[0] / (double)NROWS);
    }
}

extern "C" void kernel_launch(void* const* d_in, const int* in_sizes, int n_in,
                              void* d_out, int out_size, void* d_ws, size_t ws_size,
                              hipStream_t stream)
{
    const float* dp = (const float*)d_in[0];   // delta_pred [B,56]
    const float* bx = (const float*)d_in[1];   // batch_x    [B,2]
    const float* S1 = (const float*)d_in[2];   // S1         [B,31]
    const float* S2 = (const float*)d_in[3];   // S2         [B,31]
    const float* w  = (const float*)d_in[4];   // scalar

    double* partial = (double*)d_ws;                         // 2048 doubles
    unsigned int* counter =
        (unsigned int*)((char*)d_ws + NBLOCKS * sizeof(double));
    float* out = (float*)d_out;

    hipMemsetAsync(counter, 0, sizeof(unsigned int), stream);  // capturable
    loss_pipe_kernel<<<NBLOCKS, NTHREADS, 0, stream>>>(
        dp, bx, S1, S2, w, partial, counter, out);
}

// Round 6
// 99.009 us; speedup vs baseline: 2.7770x; 2.7770x over previous
//
#include <hip/hip_runtime.h>

// Problem: N=30, K=100, ALPHA=0.5, B=1048576
// Direct-load variant: no LDS staging, no barriers, no DMA.
// 4 lanes per row (seg=0..3, 7 delta-pairs each) -> every wave instruction
// touches a dense ~2-3.5KB span of 16 consecutive rows; reuse window is the
// in-register u/i loop of the same wave -> L1/L2 resident, no HBM over-fetch.
#define NROWS    1048576
#define NBLOCKS  2048
#define NTHREADS 256
#define ROWS_PER_BLOCK (NROWS / NBLOCKS)        // 512 consecutive rows/block
#define ROWS_PER_ITER  (NTHREADS / 4)           // 64 rows per block-iteration
#define NITER (ROWS_PER_BLOCK / ROWS_PER_ITER)  // 8

__global__ __launch_bounds__(NTHREADS) void loss_direct_kernel(
    const float* __restrict__ dp,   // [B, 56]
    const float* __restrict__ bx,   // [B, 2]
    const float* __restrict__ S1,   // [B, 31]
    const float* __restrict__ S2,   // [B, 31]
    const float* __restrict__ wp,   // scalar
    double* __restrict__ partial)   // [NBLOCKS]
{
    const int tid = threadIdx.x;
    const int seg = tid & 3;                 // 0..3
    const int sb  = 7 * seg;                 // pair base for this segment
    const float w = *wp;

    const int row0 = blockIdx.x * ROWS_PER_BLOCK + (tid >> 2);
    double acc = 0.0;

    #pragma unroll 2
    for (int j = 0; j < NITER; ++j) {
        const int    row   = row0 + j * ROWS_PER_ITER;
        const float* s1row = S1 + (size_t)row * 31;
        const float* s2row = S2 + (size_t)row * 31;
        const float2* dprow = reinterpret_cast<const float2*>(dp + (size_t)row * 56);
        const float2  b2    = *reinterpret_cast<const float2*>(bx + (size_t)row * 2);

        // 9 S-values per array for this segment (indices sb..sb+8)
        float s1v[9], s2v[9];
        #pragma unroll
        for (int i = 0; i < 9; ++i) { s1v[i] = s1row[sb + i]; s2v[i] = s2row[sb + i]; }

        // pairs p = sb+u : dS[p] = S[p+2] - S[p+1] = v[u+2] - v[u+1]
        float sum = 0.0f;
        #pragma unroll
        for (int u = 0; u < 7; ++u) {
            const float2 d = dprow[sb + u];  // (d1[p], d2[p])
            sum += d.x * (s1v[u + 2] - s1v[u + 1]) + d.y * (s2v[u + 2] - s2v[u + 1]);
        }
        const float t0 = b2.x * (s1v[1] - s1v[0]) + b2.y * (s2v[1] - s2v[0]);
        sum += (seg == 0) ? t0 : 0.0f;       // boundary term once per row

        sum += __shfl_xor(sum, 1);           // combine the 4 segments
        sum += __shfl_xor(sum, 2);

        const float liab = fmaxf(s1row[30] - 100.0f, 0.0f);   // broadcast load
        const float loss = w + fmaxf(liab - sum - w, 0.0f) * 2.0f;  // /(1-ALPHA)
        if (seg == 0) acc += (double)loss;
    }

    // deterministic block reduction (double)
    __shared__ double sm[NTHREADS];
    sm[tid] = acc;
    __syncthreads();
    #pragma unroll
    for (int s = NTHREADS / 2; s > 0; s >>= 1) {
        if (tid < s) sm[tid] += sm[tid + s];
        __syncthreads();
    }
    if (tid == 0) partial[blockIdx.x] = sm[0];
}

__global__ __launch_bounds__(NTHREADS) void loss_final_kernel(
    const double* __restrict__ partial, float* __restrict__ out)
{
    double acc = 0.0;
    for (int i = threadIdx.x; i < NBLOCKS; i += NTHREADS) acc += partial[i];
    __shared__ double sm[NTHREADS];
    sm[threadIdx.x] = acc;
    __syncthreads();
    #pragma unroll
    for (int s = NTHREADS / 2; s > 0; s >>= 1) {
        if (threadIdx.x < s) sm[threadIdx.x] += sm[threadIdx.x + s];
        __syncthreads();
    }
    if (threadIdx.x == 0) out[0] = (float)(sm[0] / (double)NROWS);
}

extern "C" void kernel_launch(void* const* d_in, const int* in_sizes, int n_in,
                              void* d_out, int out_size, void* d_ws, size_t ws_size,
                              hipStream_t stream)
{
    const float* dp = (const float*)d_in[0];   // delta_pred [B,56]
    const float* bx = (const float*)d_in[1];   // batch_x    [B,2]
    const float* S1 = (const float*)d_in[2];   // S1         [B,31]
    const float* S2 = (const float*)d_in[3];   // S2         [B,31]
    const float* w  = (const float*)d_in[4];   // scalar

    double* partial = (double*)d_ws;           // NBLOCKS doubles (16 KiB)
    float* out = (float*)d_out;

    loss_direct_kernel<<<NBLOCKS, NTHREADS, 0, stream>>>(dp, bx, S1, S2, w, partial);
    loss_final_kernel<<<1, NTHREADS, 0, stream>>>(partial, out);
}

// Round 7
// 91.445 us; speedup vs baseline: 3.0067x; 1.0827x over previous
//
#include <hip/hip_runtime.h>

// Problem: N=30, K=100, ALPHA=0.5, B=1048576
#define NROWS    1048576
#define TILE     64                         // rows per tile
#define NBLOCKS  2048
#define NTHREADS 256
#define TILES_PER_BLOCK 8                   // 16384 tiles / 2048 blocks

// Per-tile global byte sizes (contiguous rows)
#define DP_TILE_B (TILE * 224)              // 14336 = 14 x 1KB
#define S_TILE_B  (TILE * 124)              // 7936  = 7 x 1KB + 3 x 256B
#define BX_TILE_B (TILE * 8)                // 512   = 2 x 256B

// LDS layout inside one buffer (no padding needed; all 16B-aligned)
#define LDS_DP 0
#define LDS_S1 14336
#define LDS_S2 22272
#define LDS_BX 30208
#define BUF_B  30720                        // 30 KB per buffer, x2 buffers

// Async global->LDS DMA. LDS dest = wave-uniform base (+ lane*width implicit).
#define GLDS16(g, l) __builtin_amdgcn_global_load_lds(                         \
    (const __attribute__((address_space(1))) void*)(g),                        \
    (__attribute__((address_space(3))) void*)(l), 16, 0, 0)
#define GLDS4(g, l) __builtin_amdgcn_global_load_lds(                          \
    (const __attribute__((address_space(1))) void*)(g),                        \
    (__attribute__((address_space(3))) void*)(l), 4, 0, 0)

// Each wave issues EXACTLY 9 DMA instructions (uniform vmcnt bookkeeping).
__device__ __forceinline__ void stage_tile(unsigned char* buf,
    const char* dpg, const char* s1g, const char* s2g, const char* bxg,
    int wv, int lane)
{
    if (wv == 0) {
        #pragma unroll
        for (int c = 0; c < 9; ++c)
            GLDS16(dpg + c * 1024 + lane * 16, buf + LDS_DP + c * 1024);
    } else if (wv == 1) {
        #pragma unroll
        for (int c = 9; c < 14; ++c)
            GLDS16(dpg + c * 1024 + lane * 16, buf + LDS_DP + c * 1024);
        #pragma unroll
        for (int c = 0; c < 4; ++c)
            GLDS16(s1g + c * 1024 + lane * 16, buf + LDS_S1 + c * 1024);
    } else if (wv == 2) {
        #pragma unroll
        for (int c = 4; c < 7; ++c)
            GLDS16(s1g + c * 1024 + lane * 16, buf + LDS_S1 + c * 1024);
        #pragma unroll
        for (int k = 0; k < 3; ++k)
            GLDS4(s1g + 7168 + k * 256 + lane * 4, buf + LDS_S1 + 7168 + k * 256);
        #pragma unroll
        for (int c = 0; c < 3; ++c)
            GLDS16(s2g + c * 1024 + lane * 16, buf + LDS_S2 + c * 1024);
    } else {
        #pragma unroll
        for (int c = 3; c < 7; ++c)
            GLDS16(s2g + c * 1024 + lane * 16, buf + LDS_S2 + c * 1024);
        #pragma unroll
        for (int k = 0; k < 3; ++k)
            GLDS4(s2g + 7168 + k * 256 + lane * 4, buf + LDS_S2 + 7168 + k * 256);
        #pragma unroll
        for (int k = 0; k < 2; ++k)
            GLDS4(bxg + k * 256 + lane * 4, buf + LDS_BX + k * 256);
    }
}

// All 256 threads compute: 4 lanes per row, 7 pairs each, shuffle-combine.
__device__ __forceinline__ void compute_tile(const unsigned char* buf,
    int row, int seg, float w, double& acc)
{
    const float*  s1row = (const float*)(buf + LDS_S1 + row * 124);
    const float*  s2row = (const float*)(buf + LDS_S2 + row * 124);
    const float2* dprow = (const float2*)(buf + LDS_DP + row * 224);
    const float2  b2    = *(const float2*)(buf + LDS_BX + row * 8);

    const int sb = 7 * seg;                 // this seg's S base index
    float s1v[9], s2v[9];
    #pragma unroll
    for (int i = 0; i < 9; ++i) { s1v[i] = s1row[sb + i]; s2v[i] = s2row[sb + i]; }

    // pairs p = 7*seg + u : dS[p] = S[p+2]-S[p+1] = v[u+2]-v[u+1]
    float sum = 0.0f;
    #pragma unroll
    for (int u = 0; u < 7; ++u) {
        const float2 d = dprow[sb + u];     // (d1[p], d2[p])
        sum += d.x * (s1v[u + 2] - s1v[u + 1]) + d.y * (s2v[u + 2] - s2v[u + 1]);
    }
    const float t0 = b2.x * (s1v[1] - s1v[0]) + b2.y * (s2v[1] - s2v[0]);
    sum += (seg == 0) ? t0 : 0.0f;          // boundary term once per row

    sum += __shfl_xor(sum, 1);              // combine 4 segments
    sum += __shfl_xor(sum, 2);

    const float liab = fmaxf(s1row[30] - 100.0f, 0.0f);
    const float loss = w + fmaxf(liab - sum - w, 0.0f) * 2.0f;   // /(1-ALPHA)
    if (seg == 0) acc += (double)loss;
}

__global__ __launch_bounds__(NTHREADS) void loss_pipe_kernel(
    const float* __restrict__ dp, const float* __restrict__ bx,
    const float* __restrict__ S1, const float* __restrict__ S2,
    const float* __restrict__ wp, double* __restrict__ partial)
{
    __shared__ __align__(16) unsigned char lds[2 * BUF_B];
    __shared__ double sm[NTHREADS];

    const int tid  = threadIdx.x;
    const int lane = tid & 63;
    const int wv   = tid >> 6;
    const int row  = tid >> 2;              // 0..63
    const int seg  = tid & 3;               // 0..3
    const float w  = *wp;

    const long tile0 = (long)blockIdx.x * TILES_PER_BLOCK;
    double acc = 0.0;

    // prologue: stage tile 0 into buf0
    stage_tile(lds,
               (const char*)dp + tile0 * DP_TILE_B,
               (const char*)S1 + tile0 * S_TILE_B,
               (const char*)S2 + tile0 * S_TILE_B,
               (const char*)bx + tile0 * BX_TILE_B, wv, lane);

    for (int t = 0; t < TILES_PER_BLOCK - 1; ++t) {
        const long nt = tile0 + t + 1;
        stage_tile(lds + ((t + 1) & 1) * BUF_B,     // prefetch next tile
                   (const char*)dp + nt * DP_TILE_B,
                   (const char*)S1 + nt * S_TILE_B,
                   (const char*)S2 + nt * S_TILE_B,
                   (const char*)bx + nt * BX_TILE_B, wv, lane);
        // counted wait: current tile's 9 DMAs done, prefetch's 9 stay in flight
        asm volatile("s_waitcnt vmcnt(9)" ::: "memory");
        __builtin_amdgcn_s_barrier();
        compute_tile(lds + (t & 1) * BUF_B, row, seg, w, acc);
        __builtin_amdgcn_s_barrier();       // all done reading before overwrite
    }
    // epilogue: last tile
    asm volatile("s_waitcnt vmcnt(0)" ::: "memory");
    __builtin_amdgcn_s_barrier();
    compute_tile(lds + ((TILES_PER_BLOCK - 1) & 1) * BUF_B, row, seg, w, acc);

    // deterministic block reduction (double)
    sm[tid] = acc;
    __syncthreads();
    #pragma unroll
    for (int s = NTHREADS / 2; s > 0; s >>= 1) {
        if (tid < s) sm[tid] += sm[tid + s];
        __syncthreads();
    }
    if (tid == 0) partial[blockIdx.x] = sm[0];
}

__global__ __launch_bounds__(NTHREADS) void loss_final_kernel(
    const double* __restrict__ partial, float* __restrict__ out)
{
    double acc = 0.0;
    for (int i = threadIdx.x; i < NBLOCKS; i += NTHREADS) acc += partial[i];
    __shared__ double sm[NTHREADS];
    sm[threadIdx.x] = acc;
    __syncthreads();
    #pragma unroll
    for (int s = NTHREADS / 2; s > 0; s >>= 1) {
        if (threadIdx.x < s) sm[threadIdx.x] += sm[threadIdx.x + s];
        __syncthreads();
    }
    if (threadIdx.x == 0) out[0] = (float)(sm[0] / (double)NROWS);
}

extern "C" void kernel_launch(void* const* d_in, const int* in_sizes, int n_in,
                              void* d_out, int out_size, void* d_ws, size_t ws_size,
                              hipStream_t stream)
{
    const float* dp = (const float*)d_in[0];   // delta_pred [B,56]
    const float* bx = (const float*)d_in[1];   // batch_x    [B,2]
    const float* S1 = (const float*)d_in[2];   // S1         [B,31]
    const float* S2 = (const float*)d_in[3];   // S2         [B,31]
    const float* w  = (const float*)d_in[4];   // scalar

    double* partial = (double*)d_ws;           // NBLOCKS doubles (16 KiB)
    float* out = (float*)d_out;

    loss_pipe_kernel<<<NBLOCKS, NTHREADS, 0, stream>>>(dp, bx, S1, S2, w, partial);
    loss_final_kernel<<<1, NTHREADS, 0, stream>>>(partial, out);
}